// Round 1
// baseline (264.206 us; speedup 1.0000x reference)
//
#include <hip/hip_runtime.h>

#define NCLS 20
#define NBIN 512
#define BATCH 4
#define HWSZ (512*1024)
#define NPIX (BATCH*HWSZ)

// ---------------------------------------------------------------------------
// Kernel 1: per-class error histograms.
// Each pixel: softmax over 20 channels, then for each class c bin the error
// e = valid ? (label==c ? 1-p : p) : 0 into one of NBIN uniform bins in [0,1].
// LDS histogram packs count (low16) + fg count (high16) per bin; per-block
// per-class count <= 4096 pixels so 16 bits suffice.
// ---------------------------------------------------------------------------
__global__ void hist_kernel(const float* __restrict__ logits,
                            const int* __restrict__ labels,
                            unsigned long long* __restrict__ ghist)
{
    __shared__ unsigned int lh[NCLS * NBIN];   // 40 KB
    for (int i = threadIdx.x; i < NCLS * NBIN; i += blockDim.x) lh[i] = 0u;
    __syncthreads();

    const int tid = blockIdx.x * blockDim.x + threadIdx.x;
    const int nthreads = gridDim.x * blockDim.x;

    for (int n = tid; n < NPIX; n += nthreads) {
        const int b  = n >> 19;            // n / HWSZ
        const int hw = n & (HWSZ - 1);     // n % HWSZ
        const float* base = logits + (size_t)b * NCLS * HWSZ + hw;

        float x[NCLS];
        float m = -1e30f;
#pragma unroll
        for (int c = 0; c < NCLS; c++) {
            x[c] = base[(size_t)c * HWSZ];
            m = fmaxf(m, x[c]);
        }
        float Z = 0.f;
#pragma unroll
        for (int c = 0; c < NCLS; c++) {
            x[c] = __expf(x[c] - m);
            Z += x[c];
        }
        const float invZ = 1.f / Z;

        const int lbl = labels[n];
        const bool valid = (lbl != 0);

#pragma unroll
        for (int c = 0; c < NCLS; c++) {
            const float p = x[c] * invZ;
            const bool fg = valid && (lbl == c);
            const float e = valid ? (fg ? 1.f - p : p) : 0.f;
            int bin = (int)(e * (float)NBIN);
            bin = bin > (NBIN - 1) ? (NBIN - 1) : bin;
            atomicAdd(&lh[c * NBIN + bin], fg ? 0x10001u : 1u);
        }
    }
    __syncthreads();

    // merge into global u64 histogram: count in low32, fg in high32
    for (int i = threadIdx.x; i < NCLS * NBIN; i += blockDim.x) {
        const unsigned v = lh[i];
        if (v) {
            unsigned long long add =
                (unsigned long long)(v & 0xFFFFu) |
                ((unsigned long long)(v >> 16) << 32);
            atomicAdd(&ghist[i], add);
        }
    }
}

// ---------------------------------------------------------------------------
// Kernel 2: per-class Lovasz scan over bins (descending error order).
// One wave (64 lanes) per class. J(F,T) = 1 - (gts-F)/(gts+T-F); with T=F=0
// this gives J=0 (gts/gts), matching the reference's implicit J_0 = 0.
// loss += bin_center * (J_after_bin - J_before_bin).
// ---------------------------------------------------------------------------
__global__ void scan_kernel(const unsigned long long* __restrict__ ghist,
                            float* __restrict__ cls)
{
    const int c = blockIdx.x;
    const int lane = threadIdx.x;   // 0..63, one wave
    const unsigned long long* h = ghist + c * NBIN;

    // total fg count (gts)
    unsigned fgsum = 0;
    for (int j = lane; j < NBIN; j += 64)
        fgsum += (unsigned)(h[j] >> 32);
    for (int off = 32; off; off >>= 1)
        fgsum += __shfl_down(fgsum, off);
    const unsigned gts = __shfl(fgsum, 0);

    float loss = 0.f;
    if (gts > 0) {
        const float fgts = (float)gts;
        unsigned Tc = 0, Fc = 0;    // carry (cumulative from higher bins)
        float acc = 0.f;
        for (int chunk = 0; chunk < NBIN / 64; chunk++) {
            const int k = NBIN - 1 - (chunk * 64 + lane);  // descending bins
            const unsigned long long v = h[k];
            const unsigned cnt = (unsigned)(v & 0xFFFFFFFFull);
            const unsigned fg  = (unsigned)(v >> 32);

            // inclusive wave prefix scan of (cnt, fg)
            unsigned ci = cnt, fi = fg;
            for (int off = 1; off < 64; off <<= 1) {
                const unsigned cu = __shfl_up(ci, off);
                const unsigned fu = __shfl_up(fi, off);
                if (lane >= off) { ci += cu; fi += fu; }
            }
            const unsigned T1 = Tc + ci, F1 = Fc + fi;
            const unsigned T0 = T1 - cnt, F0 = F1 - fg;

            const float J1 = 1.f - (fgts - (float)F1) /
                                   (fgts + (float)T1 - (float)F1);
            const float J0 = 1.f - (fgts - (float)F0) /
                                   (fgts + (float)T0 - (float)F0);
            const float center = ((float)k + 0.5f) * (1.0f / (float)NBIN);
            acc += center * (J1 - J0);

            Tc = __shfl(T1, 63);
            Fc = __shfl(F1, 63);
        }
        for (int off = 32; off; off >>= 1)
            acc += __shfl_down(acc, off);
        loss = acc;
    }
    if (lane == 0) {
        cls[c]        = loss;
        cls[NCLS + c] = (gts > 0) ? 1.f : 0.f;
    }
}

// ---------------------------------------------------------------------------
// Kernel 3: mean over present classes.
// ---------------------------------------------------------------------------
__global__ void finalize_kernel(const float* __restrict__ cls,
                                float* __restrict__ out)
{
    if (threadIdx.x == 0 && blockIdx.x == 0) {
        float sl = 0.f, sp = 0.f;
        for (int c = 0; c < NCLS; c++) {
            sl += cls[c] * cls[NCLS + c];
            sp += cls[NCLS + c];
        }
        out[0] = sl / fmaxf(sp, 1.f);
    }
}

extern "C" void kernel_launch(void* const* d_in, const int* in_sizes, int n_in,
                              void* d_out, int out_size, void* d_ws, size_t ws_size,
                              hipStream_t stream)
{
    const float* logits = (const float*)d_in[0];
    const int*   labels = (const int*)d_in[1];

    unsigned long long* ghist = (unsigned long long*)d_ws;
    float* cls = (float*)((char*)d_ws + (size_t)NCLS * NBIN * 8);

    // zero histogram + class buffers (ws is poisoned 0xAA before each call)
    hipMemsetAsync(d_ws, 0, (size_t)NCLS * NBIN * 8 + 2 * NCLS * 4, stream);

    hist_kernel<<<512, 1024, 0, stream>>>(logits, labels, ghist);
    scan_kernel<<<NCLS, 64, 0, stream>>>(ghist, cls);
    finalize_kernel<<<1, 1, 0, stream>>>(cls, (float*)d_out);
}